// Round 14
// baseline (256.714 us; speedup 1.0000x reference)
//
#include <hip/hip_runtime.h>
#include <cstdint>
#include <math.h>

constexpr float NEG_SLOPE = 0.2f;

__device__ __forceinline__ float lrelu(float v) { return v > 0.0f ? v : NEG_SLOPE * v; }

// bf16 pack/unpack (RNE)
__device__ __forceinline__ unsigned short f2bf(float f) {
    uint32_t u = __float_as_uint(f);
    uint32_t r = (u + 0x7fffu + ((u >> 16) & 1u)) >> 16;
    return (unsigned short)r;
}
__device__ __forceinline__ float bf2f(unsigned short v) { return __uint_as_float((uint32_t)v << 16); }
__device__ __forceinline__ float bflo(uint32_t v) { return __uint_as_float(v << 16); }
__device__ __forceinline__ float bfhi(uint32_t v) { return __uint_as_float(v & 0xffff0000u); }

typedef short bf16x8 __attribute__((ext_vector_type(8)));   // 8 bf16 (4 VGPRs)
typedef float f32x4 __attribute__((ext_vector_type(4)));

// ---------------- K0: attB prebake (1 block): vs/vd = Wg^T.att as hi/lo B-fragment cols -
// attB layout [16 cols][32 words]: cols 0-3 vsH, 4-7 vsL, 8-11 vdH, 12-15 vdL.
__global__ void k_wprep1(const float* __restrict__ Wg,
                         const float* __restrict__ att_s, const float* __restrict__ att_d,
                         uint32_t* __restrict__ attB)
{
    __shared__ float vs_l[256], vd_l[256];
    const int tid = threadIdx.x;
    int h = tid >> 6, k = tid & 63;
    float s = 0.f, d = 0.f;
    for (int dd = 0; dd < 64; ++dd) {
        float w = Wg[(size_t)(h * 64 + dd) * 64 + k];
        s += w * att_s[h * 64 + dd];
        d += w * att_d[h * 64 + dd];
    }
    vs_l[tid] = s; vd_l[tid] = d;
    __syncthreads();
    for (int w = tid; w < 512; w += 256) {
        int col = w >> 5, k2 = w & 31;
        int hh = col & 3;
        int plane = (col >> 2) & 1;    // 0 hi, 1 lo
        const float* buf = (col >> 3) ? vd_l : vs_l;
        float v0 = buf[hh * 64 + 2 * k2];
        float v1 = buf[hh * 64 + 2 * k2 + 1];
        unsigned short h0 = f2bf(v0), h1 = f2bf(v1);
        if (plane) { h0 = f2bf(v0 - bf2f(h0)); h1 = f2bf(v1 - bf2f(h1)); }
        attB[w] = (uint32_t)h0 | ((uint32_t)h1 << 16);
    }
}

// ---------------- K2 (fused): mask ballot (range A) + deg histogram (range B) ---------
__global__ void k_maskdeg(const float* __restrict__ mask, const int* __restrict__ ei,
                          unsigned long long* __restrict__ mbits, int* __restrict__ deg,
                          int* __restrict__ startg, int N, int E, int nbMask)
{
    int tid = threadIdx.x;
    if ((int)blockIdx.x < nbMask) {
        if (blockIdx.x == 0 && tid < 64) startg[tid] = N;   // init before gemm1m boundary detect
        int wid  = (blockIdx.x * 256 + tid) >> 6;
        int lane = tid & 63;
        if (wid >= N) return;
        float v = mask[(size_t)wid * 64 + lane];
        unsigned long long b = __ballot(v > 0.0f);
        if (lane == 0) mbits[wid] = b;
    } else {
        int e = (blockIdx.x - nbMask) * 256 + tid;
        if (e >= E) return;
        atomicAdd(deg + ei[E + e], 1);
    }
}

// ---------------- K3 (MFMA, round-11 staging + fused a_s/a_d): xwp = x @ Wg^T ---------
__launch_bounds__(256)
__global__ void k_gemm1m_att(const float* __restrict__ x, const float* __restrict__ Wg,
                             const uint32_t* __restrict__ attB, const int* __restrict__ batch_idx,
                             uint32_t* __restrict__ xwp, float* __restrict__ a_s,
                             float* __restrict__ a_d, int* __restrict__ startg, int N)
{
    __shared__ __align__(16) uint32_t AsH[2048];   // 64 rows x 32 k-pairs (bf16x2)
    __shared__ __align__(16) uint32_t AsL[2048];
    __shared__ __align__(16) uint32_t BsH[8192];   // 256 cols x 32 k-pairs
    const int tid = threadIdx.x;
    const int r0  = blockIdx.x * 64;

    for (int idx = tid; idx < 2048; idx += 256) {
        int r = idx >> 5, k2 = idx & 31;
        float2 v = make_float2(0.f, 0.f);
        if (r0 + r < N) v = *(const float2*)&x[(size_t)(r0 + r) * 64 + 2 * k2];
        unsigned short h0 = f2bf(v.x), h1 = f2bf(v.y);
        unsigned short l0 = f2bf(v.x - bf2f(h0)), l1 = f2bf(v.y - bf2f(h1));
        int di = (r * 32 + k2) ^ ((r & 7) << 2);
        AsH[di] = (uint32_t)h0 | ((uint32_t)h1 << 16);
        AsL[di] = (uint32_t)l0 | ((uint32_t)l1 << 16);
    }
    for (int idx = tid; idx < 8192; idx += 256) {
        int c = idx >> 5, k2 = idx & 31;
        float2 v = *(const float2*)&Wg[(size_t)c * 64 + 2 * k2];
        int di = (c * 32 + k2) ^ ((c & 7) << 2);
        BsH[di] = (uint32_t)f2bf(v.x) | ((uint32_t)f2bf(v.y) << 16);
    }
    if (tid < 64 && (r0 + tid) < N) {
        int i = r0 + tid;
        int b = batch_idx[i];
        int pb = (i > 0) ? batch_idx[i - 1] : -1;
        if (b != pb) startg[b] = i;
    }
    __syncthreads();

    const int lane = tid & 63;
    const int wv   = tid >> 6;
    const int rl   = lane & 15;
    const int kg   = lane >> 4;
    const int ct0  = (wv & 1) * 2 + (wv >> 1) * 8;
    const int swz  = (rl & 7) << 2;

    f32x4 acc[4][4];
    #pragma unroll
    for (int r = 0; r < 4; ++r)
        #pragma unroll
        for (int cs = 0; cs < 4; ++cs) acc[r][cs] = (f32x4){0.f, 0.f, 0.f, 0.f};
    f32x4 accA = (f32x4){0.f, 0.f, 0.f, 0.f};

    #pragma unroll
    for (int ks = 0; ks < 2; ++ks) {
        bf16x8 aH[4], aL[4], bH[4];
        #pragma unroll
        for (int r = 0; r < 4; ++r) {
            int ui = (((r * 16 + rl) * 32) + ks * 16 + kg * 4) ^ swz;
            aH[r] = *(const bf16x8*)&AsH[ui];
            aL[r] = *(const bf16x8*)&AsL[ui];
        }
        #pragma unroll
        for (int cs = 0; cs < 4; ++cs) {
            int ct = ct0 + (cs & 1) + (cs >> 1) * 4;
            int ui = (((ct * 16 + rl) * 32) + ks * 16 + kg * 4) ^ swz;
            bH[cs] = *(const bf16x8*)&BsH[ui];
        }
        bf16x8 bAtt = *(const bf16x8*)(attB + (rl * 32 + ks * 16 + kg * 4));
        #pragma unroll
        for (int r = 0; r < 4; ++r)
            #pragma unroll
            for (int cs = 0; cs < 4; ++cs) {
                acc[r][cs] = __builtin_amdgcn_mfma_f32_16x16x32_bf16(aH[r], bH[cs], acc[r][cs], 0, 0, 0);
                acc[r][cs] = __builtin_amdgcn_mfma_f32_16x16x32_bf16(aL[r], bH[cs], acc[r][cs], 0, 0, 0);
            }
        accA = __builtin_amdgcn_mfma_f32_16x16x32_bf16(aH[wv], bAtt, accA, 0, 0, 0);
        accA = __builtin_amdgcn_mfma_f32_16x16x32_bf16(aL[wv], bAtt, accA, 0, 0, 0);
    }

    #pragma unroll
    for (int r = 0; r < 4; ++r) {
        #pragma unroll
        for (int reg = 0; reg < 4; ++reg) {
            int row = r0 + r * 16 + kg * 4 + reg;
            if (row < N) {
                #pragma unroll
                for (int p = 0; p < 2; ++p) {
                    int c_lo = (ct0 + p) * 16 + rl;
                    int wrd  = ((c_lo >> 7) << 6) | (c_lo & 63);
                    uint32_t lo = f2bf(acc[r][p][reg]);
                    uint32_t hi = f2bf(acc[r][p + 2][reg]);
                    xwp[(size_t)row * 128 + wrd] = lo | (hi << 16);
                }
            }
        }
    }
    // att epilogue: cols rl and rl+4 hold hi/lo planes -> sum via shfl_xor(4)
    #pragma unroll
    for (int reg = 0; reg < 4; ++reg) {
        float v = accA[reg] + __shfl_xor(accA[reg], 4);
        int row = r0 + wv * 16 + kg * 4 + reg;
        if (row < N) {
            if (rl < 4)                  a_s[(size_t)row * 4 + rl]       = v;
            else if (rl >= 8 && rl < 12) a_d[(size_t)row * 4 + (rl - 8)] = v;
        }
    }
}

// ---------------- K5/K6/K7: multi-block exclusive scan (known-good) -------------------
__global__ void k_scan1(const int* __restrict__ deg, int* __restrict__ off,
                        int* __restrict__ bsum, int N)
{
    __shared__ int s[256];
    int t = threadIdx.x;
    int i = blockIdx.x * 256 + t;
    int v = (i < N) ? deg[i] : 0;
    s[t] = v; __syncthreads();
    for (int o = 1; o < 256; o <<= 1) {
        int u = (t >= o) ? s[t - o] : 0;
        __syncthreads();
        s[t] += u;
        __syncthreads();
    }
    int incl = s[t];
    if (i < N) off[i] = incl - v;
    if (t == 255) bsum[blockIdx.x] = incl;
}

__global__ void k_scan2(const int* __restrict__ bsum, int* __restrict__ bpre,
                        int* __restrict__ off, const int* __restrict__ startg,
                        float* __restrict__ invs, int NB, int N)
{
    __shared__ int s[256];
    int t = threadIdx.x;
    int v = (t < NB) ? bsum[t] : 0;
    s[t] = v; __syncthreads();
    for (int o = 1; o < 256; o <<= 1) {
        int u = (t >= o) ? s[t - o] : 0;
        __syncthreads();
        s[t] += u;
        __syncthreads();
    }
    if (t < NB) bpre[t] = s[t] - v;
    if (t == 255) off[N] = s[255];
    if (t < 64) {
        int st = startg[t];
        int en = N;
        for (int g2 = t + 1; g2 < 64; ++g2) en = min(en, startg[g2]);
        int d = en - st;
        float dv = (d > 0) ? (float)d : 1.0f;
        invs[t] = 1.0f / sqrtf(dv);
    }
}

__global__ void k_scan3(int* __restrict__ off, int* __restrict__ cursor,
                        const int* __restrict__ bpre, int N)
{
    int i = blockIdx.x * blockDim.x + threadIdx.x;
    if (i >= N) return;
    int v = off[i] + bpre[blockIdx.x];
    off[i] = v;
    cursor[i] = v;
}

// ---------------- K_fill: CSR fill + mask OR scatter (merged) -------------------------
__global__ void k_fill(const int* __restrict__ ei, int* __restrict__ cursor,
                       int* __restrict__ csr,
                       const unsigned long long* __restrict__ mbits,
                       unsigned long long* __restrict__ magg, int E)
{
    int e = blockIdx.x * blockDim.x + threadIdx.x;
    if (e >= E) return;
    int r = ei[e];
    int c = ei[E + e];
    unsigned long long b = mbits[c];
    if ((magg[r] & b) != b) atomicOr(magg + r, b);
    int pos = atomicAdd(cursor + c, 1);
    csr[pos] = r;
}

// ---------------- K9 (v7): inline denominators, bf16 tb output (unchanged) ------------
__launch_bounds__(256)
__global__ void k_main7(const uint32_t* __restrict__ xwp,
                        const float* __restrict__ a_s,
                        const float* __restrict__ a_d,
                        const int* __restrict__ off,
                        const int* __restrict__ csr,
                        const unsigned long long* __restrict__ magg,
                        const float* __restrict__ bias,
                        uint32_t* __restrict__ tbp, int N)
{
    __shared__ __align__(16) uint32_t su[4][64];
    __shared__ __align__(16) float2 e01s[4][64];
    __shared__ __align__(16) float2 e23s[4][64];

    const int lane = threadIdx.x & 63;
    const int wv   = threadIdx.x >> 6;
    const int wid  = blockIdx.x * 4 + wv;
    const int nw   = gridDim.x * 4;
    const int hp   = lane >> 5;
    const int d0   = (lane & 31) * 2;

    const uint2* xw2 = (const uint2*)xwp;
    const float2 bsL = *(const float2*)&bias[hp * 128 + d0];
    const float2 bsH = *(const float2*)&bias[hp * 128 + 64 + d0];
    const float2* ep = hp ? e23s[wv] : e01s[wv];

    for (int i = wid; i < N; i += nw) {
        const int beg = off[i], end = off[i + 1];
        const float4 adv = *(const float4*)(a_d + (size_t)i * 4);
        const float4 asv = *(const float4*)(a_s + (size_t)i * 4);
        const float ex0 = __expf(lrelu(asv.x + adv.x));
        const float ex1 = __expf(lrelu(asv.y + adv.y));
        const float ex2 = __expf(lrelu(asv.z + adv.z));
        const float ex3 = __expf(lrelu(asv.w + adv.w));

        const uint2 sv = xw2[(size_t)i * 64 + lane];
        const float wls = hp ? ex2 : ex0;
        const float whs = hp ? ex3 : ex1;
        float accL0 = wls * bflo(sv.x), accH0 = whs * bfhi(sv.x);
        float accL1 = wls * bflo(sv.y), accH1 = whs * bfhi(sv.y);
        float sL = 0.f, sH = 0.f;

        for (int kc = beg; kc < end; kc += 64) {
            const int cnt = min(64, end - kc);
            uint32_t sreg = 0; float e0 = 0.f, e1 = 0.f, e2 = 0.f, e3 = 0.f;
            if (lane < cnt) {
                sreg = csr[kc + lane];
                const float4 g = *(const float4*)(a_s + (size_t)sreg * 4);
                e0 = __expf(lrelu(g.x + adv.x));
                e1 = __expf(lrelu(g.y + adv.y));
                e2 = __expf(lrelu(g.z + adv.z));
                e3 = __expf(lrelu(g.w + adv.w));
            }
            su[wv][lane]   = sreg;
            e01s[wv][lane] = make_float2(e0, e1);
            e23s[wv][lane] = make_float2(e2, e3);

            int j = 0;
            for (; j + 8 <= cnt; j += 8) {
                uint4 sq0 = *(const uint4*)&su[wv][j];
                uint4 sq1 = *(const uint4*)&su[wv][j + 4];
                float2 w0 = ep[j],   w1 = ep[j+1], w2 = ep[j+2], w3 = ep[j+3];
                float2 w4 = ep[j+4], w5 = ep[j+5], w6 = ep[j+6], w7 = ep[j+7];
                uint2 v0 = xw2[(size_t)sq0.x * 64 + lane];
                uint2 v1 = xw2[(size_t)sq0.y * 64 + lane];
                uint2 v2 = xw2[(size_t)sq0.z * 64 + lane];
                uint2 v3 = xw2[(size_t)sq0.w * 64 + lane];
                uint2 v4 = xw2[(size_t)sq1.x * 64 + lane];
                uint2 v5 = xw2[(size_t)sq1.y * 64 + lane];
                uint2 v6 = xw2[(size_t)sq1.z * 64 + lane];
                uint2 v7 = xw2[(size_t)sq1.w * 64 + lane];
                sL += w0.x + w1.x + w2.x + w3.x + w4.x + w5.x + w6.x + w7.x;
                sH += w0.y + w1.y + w2.y + w3.y + w4.y + w5.y + w6.y + w7.y;
                accL0 += w0.x * bflo(v0.x); accH0 += w0.y * bfhi(v0.x);
                accL1 += w0.x * bflo(v0.y); accH1 += w0.y * bfhi(v0.y);
                accL0 += w1.x * bflo(v1.x); accH0 += w1.y * bfhi(v1.x);
                accL1 += w1.x * bflo(v1.y); accH1 += w1.y * bfhi(v1.y);
                accL0 += w2.x * bflo(v2.x); accH0 += w2.y * bfhi(v2.x);
                accL1 += w2.x * bflo(v2.y); accH1 += w2.y * bfhi(v2.y);
                accL0 += w3.x * bflo(v3.x); accH0 += w3.y * bfhi(v3.x);
                accL1 += w3.x * bflo(v3.y); accH1 += w3.y * bfhi(v3.y);
                accL0 += w4.x * bflo(v4.x); accH0 += w4.y * bfhi(v4.x);
                accL1 += w4.x * bflo(v4.y); accH1 += w4.y * bfhi(v4.y);
                accL0 += w5.x * bflo(v5.x); accH0 += w5.y * bfhi(v5.x);
                accL1 += w5.x * bflo(v5.y); accH1 += w5.y * bfhi(v5.y);
                accL0 += w6.x * bflo(v6.x); accH0 += w6.y * bfhi(v6.x);
                accL1 += w6.x * bflo(v6.y); accH1 += w6.y * bfhi(v6.y);
                accL0 += w7.x * bflo(v7.x); accH0 += w7.y * bfhi(v7.x);
                accL1 += w7.x * bflo(v7.y); accH1 += w7.y * bfhi(v7.y);
            }
            for (; j + 4 <= cnt; j += 4) {
                uint4 sq = *(const uint4*)&su[wv][j];
                float2 wA = ep[j], wB = ep[j+1], wC = ep[j+2], wD = ep[j+3];
                uint2 vA = xw2[(size_t)sq.x * 64 + lane];
                uint2 vB = xw2[(size_t)sq.y * 64 + lane];
                uint2 vC = xw2[(size_t)sq.z * 64 + lane];
                uint2 vD = xw2[(size_t)sq.w * 64 + lane];
                sL += wA.x + wB.x + wC.x + wD.x;
                sH += wA.y + wB.y + wC.y + wD.y;
                accL0 += wA.x * bflo(vA.x); accH0 += wA.y * bfhi(vA.x);
                accL1 += wA.x * bflo(vA.y); accH1 += wA.y * bfhi(vA.y);
                accL0 += wB.x * bflo(vB.x); accH0 += wB.y * bfhi(vB.x);
                accL1 += wB.x * bflo(vB.y); accH1 += wB.y * bfhi(vB.y);
                accL0 += wC.x * bflo(vC.x); accH0 += wC.y * bfhi(vC.x);
                accL1 += wC.x * bflo(vC.y); accH1 += wC.y * bfhi(vC.y);
                accL0 += wD.x * bflo(vD.x); accH0 += wD.y * bfhi(vD.x);
                accL1 += wD.x * bflo(vD.y); accH1 += wD.y * bfhi(vD.y);
            }
            for (; j < cnt; ++j) {
                uint32_t s = su[wv][j];
                float2 wE = ep[j];
                uint2 v = xw2[(size_t)s * 64 + lane];
                sL += wE.x; sH += wE.y;
                accL0 += wE.x * bflo(v.x); accH0 += wE.y * bfhi(v.x);
                accL1 += wE.x * bflo(v.y); accH1 += wE.y * bfhi(v.y);
            }
        }
        const float rlo = 1.0f / (sL + wls + 1e-16f);
        const float rhi = 1.0f / (sH + whs + 1e-16f);

        const unsigned long long mb = magg[i];
        const float m0 = (float)((mb >> d0) & 1ULL);
        const float m1 = (float)((mb >> (d0 + 1)) & 1ULL);
        float oL0 = (accL0 * rlo + bsL.x) * m0, oL1 = (accL1 * rlo + bsL.y) * m1;
        float oH0 = (accH0 * rhi + bsH.x) * m0, oH1 = (accH1 * rhi + bsH.y) * m1;
        tbp[(size_t)i * 128 + hp * 64 + (lane & 31)]      = (uint32_t)f2bf(oL0) | ((uint32_t)f2bf(oL1) << 16);
        tbp[(size_t)i * 128 + hp * 64 + 32 + (lane & 31)] = (uint32_t)f2bf(oH0) | ((uint32_t)f2bf(oH1) << 16);
    }
}

// ---------------- K10 (MFMA, round-11 version): out = tbp(bf16) @ Wl^T + bl -----------
__launch_bounds__(256)
__global__ void k_gemm2m(const uint32_t* __restrict__ tbp, const float* __restrict__ Wl,
                         const float* __restrict__ bl,
                         const int* __restrict__ batch_idx, const float* __restrict__ invs,
                         float* __restrict__ out, int N)
{
    __shared__ __align__(16) uint32_t AH[2048];   // 64 rows x 32 k-pairs
    __shared__ __align__(16) uint32_t BH[2048];   // 64 cols x 32 k-pairs
    __shared__ __align__(16) uint32_t BL[2048];
    const int tid = threadIdx.x;
    const int r0  = blockIdx.x * 64;
    const int lane = tid & 63;
    const int wv   = tid >> 6;
    const int rl   = lane & 15;
    const int kg   = lane >> 4;
    const int swz  = (rl & 7) << 2;

    f32x4 acc[4];
    #pragma unroll
    for (int r = 0; r < 4; ++r) acc[r] = (f32x4){0.f, 0.f, 0.f, 0.f};

    for (int kc = 0; kc < 4; ++kc) {
        if (kc) __syncthreads();
        for (int idx = tid; idx < 2048; idx += 256) {
            int r = idx >> 5, k2 = idx & 31;
            uint32_t v = 0;
            if (r0 + r < N) v = tbp[(size_t)(r0 + r) * 128 + kc * 32 + k2];
            AH[(r * 32 + k2) ^ ((r & 7) << 2)] = v;
        }
        for (int idx = tid; idx < 2048; idx += 256) {
            int c = idx >> 5, k2 = idx & 31;
            float2 v = *(const float2*)&Wl[(size_t)c * 256 + kc * 64 + 2 * k2];
            unsigned short h0 = f2bf(v.x), h1 = f2bf(v.y);
            unsigned short l0 = f2bf(v.x - bf2f(h0)), l1 = f2bf(v.y - bf2f(h1));
            int di = (c * 32 + k2) ^ ((c & 7) << 2);
            BH[di] = (uint32_t)h0 | ((uint32_t)h1 << 16);
            BL[di] = (uint32_t)l0 | ((uint32_t)l1 << 16);
        }
        __syncthreads();

        #pragma unroll
        for (int ks = 0; ks < 2; ++ks) {
            int uib = ((wv * 16 + rl) * 32 + ks * 16 + kg * 4) ^ swz;
            bf16x8 bHf = *(const bf16x8*)&BH[uib];
            bf16x8 bLf = *(const bf16x8*)&BL[uib];
            #pragma unroll
            for (int r = 0; r < 4; ++r) {
                int ui = ((r * 16 + rl) * 32 + ks * 16 + kg * 4) ^ swz;
                bf16x8 aHf = *(const bf16x8*)&AH[ui];
                acc[r] = __builtin_amdgcn_mfma_f32_16x16x32_bf16(aHf, bHf, acc[r], 0, 0, 0);
                acc[r] = __builtin_amdgcn_mfma_f32_16x16x32_bf16(aHf, bLf, acc[r], 0, 0, 0);
            }
        }
    }

    const int col = wv * 16 + rl;
    const float blc = bl[col];
    #pragma unroll
    for (int r = 0; r < 4; ++r) {
        #pragma unroll
        for (int reg = 0; reg < 4; ++reg) {
            int row = r0 + r * 16 + kg * 4 + reg;
            if (row < N) {
                float sc = invs[batch_idx[row]];
                out[(size_t)row * 64 + col] = (acc[r][reg] + blc) * sc;
            }
        }
    }
}

// ---------------- launcher ----------------
extern "C" void kernel_launch(void* const* d_in, const int* in_sizes, int n_in,
                              void* d_out, int out_size, void* d_ws, size_t ws_size,
                              hipStream_t stream)
{
    const float* x      = (const float*)d_in[0];
    const float* mask   = (const float*)d_in[1];
    const int*   ei     = (const int*)d_in[2];
    const int*   batch  = (const int*)d_in[3];
    const float* Wg     = (const float*)d_in[4];
    const float* att_s  = (const float*)d_in[5];
    const float* att_d  = (const float*)d_in[6];
    const float* bias_g = (const float*)d_in[7];
    const float* Wl     = (const float*)d_in[8];
    const float* bl     = (const float*)d_in[9];
    float* out = (float*)d_out;

    const int N = in_sizes[0] / 64;   // 50000
    const int E = in_sizes[2] / 2;    // 800000

    char* w = (char*)d_ws;
    auto alloc = [&](size_t bytes) { char* p = w; w += (bytes + 255) & ~(size_t)255; return p; };
    uint32_t* xwp  = (uint32_t*)alloc((size_t)N * 128 * 4);
    uint32_t* tbp  = (uint32_t*)alloc((size_t)N * 128 * 4);
    float* a_s   = (float*)alloc((size_t)N * 4 * 4);
    float* a_d   = (float*)alloc((size_t)N * 4 * 4);
    unsigned long long* mbits = (unsigned long long*)alloc((size_t)N * 8);
    unsigned long long* magg  = (unsigned long long*)alloc((size_t)N * 8);
    int* deg    = (int*)alloc((size_t)N * 4);
    int* off    = (int*)alloc((size_t)(N + 1) * 4);
    int* cursor = (int*)alloc((size_t)N * 4);
    int* csr    = (int*)alloc((size_t)E * 4);
    int* bsum   = (int*)alloc(256 * 4);
    int* bpre   = (int*)alloc(256 * 4);
    int* startg = (int*)alloc(64 * 4);
    float* invs = (float*)alloc(64 * 4);
    uint32_t* attB = (uint32_t*)alloc(512 * 4);

    int nbN4  = (N + 3) / 4;
    int nbE   = (E + 255) / 256;
    int nb256 = (N + 255) / 256;

    hipMemsetAsync(deg, 0, (size_t)N * 4, stream);
    hipMemsetAsync(magg, 0, (size_t)N * 8, stream);
    k_wprep1<<<1, 256, 0, stream>>>(Wg, att_s, att_d, attB);
    k_maskdeg<<<nbN4 + nbE, 256, 0, stream>>>(mask, ei, mbits, deg, startg, N, E, nbN4);
    k_gemm1m_att<<<(N + 63) / 64, 256, 0, stream>>>(x, Wg, attB, batch, xwp, a_s, a_d, startg, N);
    k_scan1<<<nb256, 256, 0, stream>>>(deg, off, bsum, N);
    k_scan2<<<1, 256, 0, stream>>>(bsum, bpre, off, startg, invs, nb256, N);
    k_scan3<<<nb256, 256, 0, stream>>>(off, cursor, bpre, N);
    k_fill<<<nbE, 256, 0, stream>>>(ei, cursor, csr, mbits, magg, E);
    k_main7<<<2048, 256, 0, stream>>>(xwp, a_s, a_d, off, csr, magg, bias_g, tbp, N);
    k_gemm2m<<<(N + 63) / 64, 256, 0, stream>>>(tbp, Wl, bl, batch, invs, out, N);
}

// Round 15
// 235.576 us; speedup vs baseline: 1.0897x; 1.0897x over previous
//
#include <hip/hip_runtime.h>
#include <cstdint>
#include <math.h>

constexpr float NEG_SLOPE = 0.2f;

__device__ __forceinline__ float lrelu(float v) { return v > 0.0f ? v : NEG_SLOPE * v; }

// bf16 pack/unpack (RNE)
__device__ __forceinline__ unsigned short f2bf(float f) {
    uint32_t u = __float_as_uint(f);
    uint32_t r = (u + 0x7fffu + ((u >> 16) & 1u)) >> 16;
    return (unsigned short)r;
}
__device__ __forceinline__ float bf2f(unsigned short v) { return __uint_as_float((uint32_t)v << 16); }
__device__ __forceinline__ float bflo(uint32_t v) { return __uint_as_float(v << 16); }
__device__ __forceinline__ float bfhi(uint32_t v) { return __uint_as_float(v & 0xffff0000u); }

typedef short bf16x8 __attribute__((ext_vector_type(8)));   // 8 bf16 (4 VGPRs)
typedef float f32x4 __attribute__((ext_vector_type(4)));

// ---------------- K1: a_s/a_d per node + deg/magg zero + startg init (round-11) -------
__launch_bounds__(256)
__global__ void k_att2z(const float* __restrict__ x, const float* __restrict__ Wg,
                        const float* __restrict__ att_s, const float* __restrict__ att_d,
                        float* __restrict__ a_s, float* __restrict__ a_d,
                        int* __restrict__ deg, unsigned long long* __restrict__ magg,
                        int* __restrict__ startg, int N)
{
    __shared__ float vs_l[256];
    __shared__ float vd_l[256];
    int tid = threadIdx.x;
    {   // vprep: vs[h][k] = sum_d Wg[h*64+d][k] * att_s[h][d]   (Wg 64KB, L2-hot)
        int h = tid >> 6, k = tid & 63;
        float s = 0.f, d = 0.f;
        for (int dd = 0; dd < 64; ++dd) {
            float w = Wg[(size_t)(h * 64 + dd) * 64 + k];
            s += w * att_s[h * 64 + dd];
            d += w * att_d[h * 64 + dd];
        }
        vs_l[tid] = s; vd_l[tid] = d;
    }
    if (blockIdx.x == 0 && tid < 64) startg[tid] = N;
    __syncthreads();
    int i = blockIdx.x * 256 + tid;
    if (i >= N) return;
    deg[i] = 0; magg[i] = 0ULL;
    const float4* xr = (const float4*)(x + (size_t)i * 64);
    float s0=0,s1=0,s2=0,s3=0, d0=0,d1=0,d2=0,d3=0;
    #pragma unroll
    for (int q = 0; q < 16; ++q) {
        float4 xv = xr[q];
        float4 a0 = *(const float4*)&vs_l[4*q];
        float4 a1 = *(const float4*)&vs_l[64 + 4*q];
        float4 a2 = *(const float4*)&vs_l[128 + 4*q];
        float4 a3 = *(const float4*)&vs_l[192 + 4*q];
        float4 c0 = *(const float4*)&vd_l[4*q];
        float4 c1 = *(const float4*)&vd_l[64 + 4*q];
        float4 c2 = *(const float4*)&vd_l[128 + 4*q];
        float4 c3 = *(const float4*)&vd_l[192 + 4*q];
        s0 += xv.x*a0.x + xv.y*a0.y + xv.z*a0.z + xv.w*a0.w;
        s1 += xv.x*a1.x + xv.y*a1.y + xv.z*a1.z + xv.w*a1.w;
        s2 += xv.x*a2.x + xv.y*a2.y + xv.z*a2.z + xv.w*a2.w;
        s3 += xv.x*a3.x + xv.y*a3.y + xv.z*a3.z + xv.w*a3.w;
        d0 += xv.x*c0.x + xv.y*c0.y + xv.z*c0.z + xv.w*c0.w;
        d1 += xv.x*c1.x + xv.y*c1.y + xv.z*c1.z + xv.w*c1.w;
        d2 += xv.x*c2.x + xv.y*c2.y + xv.z*c2.z + xv.w*c2.w;
        d3 += xv.x*c3.x + xv.y*c3.y + xv.z*c3.z + xv.w*c3.w;
    }
    *(float4*)&a_s[(size_t)i * 4] = make_float4(s0, s1, s2, s3);
    *(float4*)&a_d[(size_t)i * 4] = make_float4(d0, d1, d2, d3);
}

// ---------------- K2 (fused): mask ballot (range A) + deg histogram (range B) ---------
__global__ void k_maskdeg(const float* __restrict__ mask, const int* __restrict__ ei,
                          unsigned long long* __restrict__ mbits, int* __restrict__ deg,
                          int N, int E, int nbMask)
{
    int tid = threadIdx.x;
    if ((int)blockIdx.x < nbMask) {
        int wid  = (blockIdx.x * 256 + tid) >> 6;
        int lane = tid & 63;
        if (wid >= N) return;
        float v = mask[(size_t)wid * 64 + lane];
        unsigned long long b = __ballot(v > 0.0f);
        if (lane == 0) mbits[wid] = b;
    } else {
        int e = (blockIdx.x - nbMask) * 256 + tid;
        if (e >= E) return;
        atomicAdd(deg + ei[E + e], 1);
    }
}

// ---------------- K3 (MFMA, round-11): xwp = x @ Wg^T + boundary detect ---------------
__launch_bounds__(256)
__global__ void k_gemm1m(const float* __restrict__ x, const float* __restrict__ Wg,
                         const int* __restrict__ batch_idx,
                         uint32_t* __restrict__ xwp, int* __restrict__ startg, int N)
{
    __shared__ __align__(16) uint32_t AsH[2048];   // 64 rows x 32 k-pairs (bf16x2)
    __shared__ __align__(16) uint32_t AsL[2048];
    __shared__ __align__(16) uint32_t BsH[8192];   // 256 cols x 32 k-pairs
    const int tid = threadIdx.x;
    const int r0  = blockIdx.x * 64;

    for (int idx = tid; idx < 2048; idx += 256) {
        int r = idx >> 5, k2 = idx & 31;
        float2 v = make_float2(0.f, 0.f);
        if (r0 + r < N) v = *(const float2*)&x[(size_t)(r0 + r) * 64 + 2 * k2];
        unsigned short h0 = f2bf(v.x), h1 = f2bf(v.y);
        unsigned short l0 = f2bf(v.x - bf2f(h0)), l1 = f2bf(v.y - bf2f(h1));
        int di = (r * 32 + k2) ^ ((r & 7) << 2);
        AsH[di] = (uint32_t)h0 | ((uint32_t)h1 << 16);
        AsL[di] = (uint32_t)l0 | ((uint32_t)l1 << 16);
    }
    for (int idx = tid; idx < 8192; idx += 256) {
        int c = idx >> 5, k2 = idx & 31;
        float2 v = *(const float2*)&Wg[(size_t)c * 64 + 2 * k2];
        int di = (c * 32 + k2) ^ ((c & 7) << 2);
        BsH[di] = (uint32_t)f2bf(v.x) | ((uint32_t)f2bf(v.y) << 16);
    }
    if (tid < 64 && (r0 + tid) < N) {
        int i = r0 + tid;
        int b = batch_idx[i];
        int pb = (i > 0) ? batch_idx[i - 1] : -1;
        if (b != pb) startg[b] = i;
    }
    __syncthreads();

    const int lane = tid & 63;
    const int wv   = tid >> 6;
    const int rl   = lane & 15;
    const int kg   = lane >> 4;
    const int ct0  = (wv & 1) * 2 + (wv >> 1) * 8;
    const int swz  = (rl & 7) << 2;

    f32x4 acc[4][4];
    #pragma unroll
    for (int r = 0; r < 4; ++r)
        #pragma unroll
        for (int cs = 0; cs < 4; ++cs) acc[r][cs] = (f32x4){0.f, 0.f, 0.f, 0.f};

    #pragma unroll
    for (int ks = 0; ks < 2; ++ks) {
        bf16x8 aH[4], aL[4], bH[4];
        #pragma unroll
        for (int r = 0; r < 4; ++r) {
            int ui = (((r * 16 + rl) * 32) + ks * 16 + kg * 4) ^ swz;
            aH[r] = *(const bf16x8*)&AsH[ui];
            aL[r] = *(const bf16x8*)&AsL[ui];
        }
        #pragma unroll
        for (int cs = 0; cs < 4; ++cs) {
            int ct = ct0 + (cs & 1) + (cs >> 1) * 4;
            int ui = (((ct * 16 + rl) * 32) + ks * 16 + kg * 4) ^ swz;
            bH[cs] = *(const bf16x8*)&BsH[ui];
        }
        #pragma unroll
        for (int r = 0; r < 4; ++r)
            #pragma unroll
            for (int cs = 0; cs < 4; ++cs) {
                acc[r][cs] = __builtin_amdgcn_mfma_f32_16x16x32_bf16(aH[r], bH[cs], acc[r][cs], 0, 0, 0);
                acc[r][cs] = __builtin_amdgcn_mfma_f32_16x16x32_bf16(aL[r], bH[cs], acc[r][cs], 0, 0, 0);
            }
    }

    #pragma unroll
    for (int r = 0; r < 4; ++r) {
        #pragma unroll
        for (int reg = 0; reg < 4; ++reg) {
            int row = r0 + r * 16 + kg * 4 + reg;
            if (row < N) {
                #pragma unroll
                for (int p = 0; p < 2; ++p) {
                    int c_lo = (ct0 + p) * 16 + rl;
                    int wrd  = ((c_lo >> 7) << 6) | (c_lo & 63);
                    uint32_t lo = f2bf(acc[r][p][reg]);
                    uint32_t hi = f2bf(acc[r][p + 2][reg]);
                    xwp[(size_t)row * 128 + wrd] = lo | (hi << 16);
                }
            }
        }
    }
}

// ---------------- K5/K6: scan (scan3 ELIMINATED via lazy bpre finalization) -----------
// scan1 writes PARTIAL off and cursor (pre-bpre); consumers add bpre[idx>>8].
__global__ void k_scan1(const int* __restrict__ deg, int* __restrict__ off,
                        int* __restrict__ cursor, int* __restrict__ bsum, int N)
{
    __shared__ int s[256];
    int t = threadIdx.x;
    int i = blockIdx.x * 256 + t;
    int v = (i < N) ? deg[i] : 0;
    s[t] = v; __syncthreads();
    for (int o = 1; o < 256; o <<= 1) {
        int u = (t >= o) ? s[t - o] : 0;
        __syncthreads();
        s[t] += u;
        __syncthreads();
    }
    int incl = s[t];
    if (i < N) { off[i] = incl - v; cursor[i] = incl - v; }
    if (t == 255) bsum[blockIdx.x] = incl;
}

__global__ void k_scan2(const int* __restrict__ bsum, int* __restrict__ bpre,
                        int* __restrict__ off, const int* __restrict__ startg,
                        float* __restrict__ invs, int NB, int N)
{
    __shared__ int s[256];
    int t = threadIdx.x;
    int v = (t < NB) ? bsum[t] : 0;
    s[t] = v; __syncthreads();
    for (int o = 1; o < 256; o <<= 1) {
        int u = (t >= o) ? s[t - o] : 0;
        __syncthreads();
        s[t] += u;
        __syncthreads();
    }
    if (t < NB) bpre[t] = s[t] - v;
    if (t == 255) off[N] = s[255];   // grand total: FINAL (no bpre correction)
    if (t < 64) {
        int st = startg[t];
        int en = N;
        for (int g2 = t + 1; g2 < 64; ++g2) en = min(en, startg[g2]);
        int d = en - st;
        float dv = (d > 0) ? (float)d : 1.0f;
        invs[t] = 1.0f / sqrtf(dv);
    }
}

// ---------------- K_fill: CSR fill + mask OR scatter; position = partial + bpre -------
__global__ void k_fill(const int* __restrict__ ei, int* __restrict__ cursor,
                       int* __restrict__ csr, const int* __restrict__ bpre,
                       const unsigned long long* __restrict__ mbits,
                       unsigned long long* __restrict__ magg, int E)
{
    int e = blockIdx.x * blockDim.x + threadIdx.x;
    if (e >= E) return;
    int r = ei[e];
    int c = ei[E + e];
    unsigned long long b = mbits[c];
    if ((magg[r] & b) != b) atomicOr(magg + r, b);
    int pos = atomicAdd(cursor + c, 1) + bpre[c >> 8];
    csr[pos] = r;
}

// ---------------- K9 (v7 + lazy offsets): inline denominators, bf16 tb output ---------
__launch_bounds__(256)
__global__ void k_main7(const uint32_t* __restrict__ xwp,
                        const float* __restrict__ a_s,
                        const float* __restrict__ a_d,
                        const int* __restrict__ off,
                        const int* __restrict__ bpre,
                        const int* __restrict__ csr,
                        const unsigned long long* __restrict__ magg,
                        const float* __restrict__ bias,
                        uint32_t* __restrict__ tbp, int N)
{
    __shared__ __align__(16) uint32_t su[4][64];
    __shared__ __align__(16) float2 e01s[4][64];
    __shared__ __align__(16) float2 e23s[4][64];

    const int lane = threadIdx.x & 63;
    const int wv   = threadIdx.x >> 6;
    const int wid  = blockIdx.x * 4 + wv;
    const int nw   = gridDim.x * 4;
    const int hp   = lane >> 5;
    const int d0   = (lane & 31) * 2;

    const uint2* xw2 = (const uint2*)xwp;
    const float2 bsL = *(const float2*)&bias[hp * 128 + d0];
    const float2 bsH = *(const float2*)&bias[hp * 128 + 64 + d0];
    const float2* ep = hp ? e23s[wv] : e01s[wv];

    for (int i = wid; i < N; i += nw) {
        const int beg = off[i] + bpre[i >> 8];
        const int end = off[i + 1] + ((i + 1 < N) ? bpre[(i + 1) >> 8] : 0);
        const float4 adv = *(const float4*)(a_d + (size_t)i * 4);
        const float4 asv = *(const float4*)(a_s + (size_t)i * 4);
        const float ex0 = __expf(lrelu(asv.x + adv.x));
        const float ex1 = __expf(lrelu(asv.y + adv.y));
        const float ex2 = __expf(lrelu(asv.z + adv.z));
        const float ex3 = __expf(lrelu(asv.w + adv.w));

        const uint2 sv = xw2[(size_t)i * 64 + lane];
        const float wls = hp ? ex2 : ex0;
        const float whs = hp ? ex3 : ex1;
        float accL0 = wls * bflo(sv.x), accH0 = whs * bfhi(sv.x);
        float accL1 = wls * bflo(sv.y), accH1 = whs * bfhi(sv.y);
        float sL = 0.f, sH = 0.f;

        for (int kc = beg; kc < end; kc += 64) {
            const int cnt = min(64, end - kc);
            uint32_t sreg = 0; float e0 = 0.f, e1 = 0.f, e2 = 0.f, e3 = 0.f;
            if (lane < cnt) {
                sreg = csr[kc + lane];
                const float4 g = *(const float4*)(a_s + (size_t)sreg * 4);
                e0 = __expf(lrelu(g.x + adv.x));
                e1 = __expf(lrelu(g.y + adv.y));
                e2 = __expf(lrelu(g.z + adv.z));
                e3 = __expf(lrelu(g.w + adv.w));
            }
            su[wv][lane]   = sreg;
            e01s[wv][lane] = make_float2(e0, e1);
            e23s[wv][lane] = make_float2(e2, e3);

            int j = 0;
            for (; j + 8 <= cnt; j += 8) {
                uint4 sq0 = *(const uint4*)&su[wv][j];
                uint4 sq1 = *(const uint4*)&su[wv][j + 4];
                float2 w0 = ep[j],   w1 = ep[j+1], w2 = ep[j+2], w3 = ep[j+3];
                float2 w4 = ep[j+4], w5 = ep[j+5], w6 = ep[j+6], w7 = ep[j+7];
                uint2 v0 = xw2[(size_t)sq0.x * 64 + lane];
                uint2 v1 = xw2[(size_t)sq0.y * 64 + lane];
                uint2 v2 = xw2[(size_t)sq0.z * 64 + lane];
                uint2 v3 = xw2[(size_t)sq0.w * 64 + lane];
                uint2 v4 = xw2[(size_t)sq1.x * 64 + lane];
                uint2 v5 = xw2[(size_t)sq1.y * 64 + lane];
                uint2 v6 = xw2[(size_t)sq1.z * 64 + lane];
                uint2 v7 = xw2[(size_t)sq1.w * 64 + lane];
                sL += w0.x + w1.x + w2.x + w3.x + w4.x + w5.x + w6.x + w7.x;
                sH += w0.y + w1.y + w2.y + w3.y + w4.y + w5.y + w6.y + w7.y;
                accL0 += w0.x * bflo(v0.x); accH0 += w0.y * bfhi(v0.x);
                accL1 += w0.x * bflo(v0.y); accH1 += w0.y * bfhi(v0.y);
                accL0 += w1.x * bflo(v1.x); accH0 += w1.y * bfhi(v1.x);
                accL1 += w1.x * bflo(v1.y); accH1 += w1.y * bfhi(v1.y);
                accL0 += w2.x * bflo(v2.x); accH0 += w2.y * bfhi(v2.x);
                accL1 += w2.x * bflo(v2.y); accH1 += w2.y * bfhi(v2.y);
                accL0 += w3.x * bflo(v3.x); accH0 += w3.y * bfhi(v3.x);
                accL1 += w3.x * bflo(v3.y); accH1 += w3.y * bfhi(v3.y);
                accL0 += w4.x * bflo(v4.x); accH0 += w4.y * bfhi(v4.x);
                accL1 += w4.x * bflo(v4.y); accH1 += w4.y * bfhi(v4.y);
                accL0 += w5.x * bflo(v5.x); accH0 += w5.y * bfhi(v5.x);
                accL1 += w5.x * bflo(v5.y); accH1 += w5.y * bfhi(v5.y);
                accL0 += w6.x * bflo(v6.x); accH0 += w6.y * bfhi(v6.x);
                accL1 += w6.x * bflo(v6.y); accH1 += w6.y * bfhi(v6.y);
                accL0 += w7.x * bflo(v7.x); accH0 += w7.y * bfhi(v7.x);
                accL1 += w7.x * bflo(v7.y); accH1 += w7.y * bfhi(v7.y);
            }
            for (; j + 4 <= cnt; j += 4) {
                uint4 sq = *(const uint4*)&su[wv][j];
                float2 wA = ep[j], wB = ep[j+1], wC = ep[j+2], wD = ep[j+3];
                uint2 vA = xw2[(size_t)sq.x * 64 + lane];
                uint2 vB = xw2[(size_t)sq.y * 64 + lane];
                uint2 vC = xw2[(size_t)sq.z * 64 + lane];
                uint2 vD = xw2[(size_t)sq.w * 64 + lane];
                sL += wA.x + wB.x + wC.x + wD.x;
                sH += wA.y + wB.y + wC.y + wD.y;
                accL0 += wA.x * bflo(vA.x); accH0 += wA.y * bfhi(vA.x);
                accL1 += wA.x * bflo(vA.y); accH1 += wA.y * bfhi(vA.y);
                accL0 += wB.x * bflo(vB.x); accH0 += wB.y * bfhi(vB.x);
                accL1 += wB.x * bflo(vB.y); accH1 += wB.y * bfhi(vB.y);
                accL0 += wC.x * bflo(vC.x); accH0 += wC.y * bfhi(vC.x);
                accL1 += wC.x * bflo(vC.y); accH1 += wC.y * bfhi(vC.y);
                accL0 += wD.x * bflo(vD.x); accH0 += wD.y * bfhi(vD.x);
                accL1 += wD.x * bflo(vD.y); accH1 += wD.y * bfhi(vD.y);
            }
            for (; j < cnt; ++j) {
                uint32_t s = su[wv][j];
                float2 wE = ep[j];
                uint2 v = xw2[(size_t)s * 64 + lane];
                sL += wE.x; sH += wE.y;
                accL0 += wE.x * bflo(v.x); accH0 += wE.y * bfhi(v.x);
                accL1 += wE.x * bflo(v.y); accH1 += wE.y * bfhi(v.y);
            }
        }
        const float rlo = 1.0f / (sL + wls + 1e-16f);
        const float rhi = 1.0f / (sH + whs + 1e-16f);

        const unsigned long long mb = magg[i];
        const float m0 = (float)((mb >> d0) & 1ULL);
        const float m1 = (float)((mb >> (d0 + 1)) & 1ULL);
        float oL0 = (accL0 * rlo + bsL.x) * m0, oL1 = (accL1 * rlo + bsL.y) * m1;
        float oH0 = (accH0 * rhi + bsH.x) * m0, oH1 = (accH1 * rhi + bsH.y) * m1;
        tbp[(size_t)i * 128 + hp * 64 + (lane & 31)]      = (uint32_t)f2bf(oL0) | ((uint32_t)f2bf(oL1) << 16);
        tbp[(size_t)i * 128 + hp * 64 + 32 + (lane & 31)] = (uint32_t)f2bf(oH0) | ((uint32_t)f2bf(oH1) << 16);
    }
}

// ---------------- K10 (MFMA, round-11): out = tbp(bf16) @ Wl^T + bl, * inv_sqrt -------
__launch_bounds__(256)
__global__ void k_gemm2m(const uint32_t* __restrict__ tbp, const float* __restrict__ Wl,
                         const float* __restrict__ bl,
                         const int* __restrict__ batch_idx, const float* __restrict__ invs,
                         float* __restrict__ out, int N)
{
    __shared__ __align__(16) uint32_t AH[2048];   // 64 rows x 32 k-pairs
    __shared__ __align__(16) uint32_t BH[2048];   // 64 cols x 32 k-pairs
    __shared__ __align__(16) uint32_t BL[2048];
    const int tid = threadIdx.x;
    const int r0  = blockIdx.x * 64;
    const int lane = tid & 63;
    const int wv   = tid >> 6;
    const int rl   = lane & 15;
    const int kg   = lane >> 4;
    const int swz  = (rl & 7) << 2;

    f32x4 acc[4];
    #pragma unroll
    for (int r = 0; r < 4; ++r) acc[r] = (f32x4){0.f, 0.f, 0.f, 0.f};

    for (int kc = 0; kc < 4; ++kc) {
        if (kc) __syncthreads();
        for (int idx = tid; idx < 2048; idx += 256) {
            int r = idx >> 5, k2 = idx & 31;
            uint32_t v = 0;
            if (r0 + r < N) v = tbp[(size_t)(r0 + r) * 128 + kc * 32 + k2];
            AH[(r * 32 + k2) ^ ((r & 7) << 2)] = v;
        }
        for (int idx = tid; idx < 2048; idx += 256) {
            int c = idx >> 5, k2 = idx & 31;
            float2 v = *(const float2*)&Wl[(size_t)c * 256 + kc * 64 + 2 * k2];
            unsigned short h0 = f2bf(v.x), h1 = f2bf(v.y);
            unsigned short l0 = f2bf(v.x - bf2f(h0)), l1 = f2bf(v.y - bf2f(h1));
            int di = (c * 32 + k2) ^ ((c & 7) << 2);
            BH[di] = (uint32_t)h0 | ((uint32_t)h1 << 16);
            BL[di] = (uint32_t)l0 | ((uint32_t)l1 << 16);
        }
        __syncthreads();

        #pragma unroll
        for (int ks = 0; ks < 2; ++ks) {
            int uib = ((wv * 16 + rl) * 32 + ks * 16 + kg * 4) ^ swz;
            bf16x8 bHf = *(const bf16x8*)&BH[uib];
            bf16x8 bLf = *(const bf16x8*)&BL[uib];
            #pragma unroll
            for (int r = 0; r < 4; ++r) {
                int ui = ((r * 16 + rl) * 32 + ks * 16 + kg * 4) ^ swz;
                bf16x8 aHf = *(const bf16x8*)&AH[ui];
                acc[r] = __builtin_amdgcn_mfma_f32_16x16x32_bf16(aHf, bHf, acc[r], 0, 0, 0);
                acc[r] = __builtin_amdgcn_mfma_f32_16x16x32_bf16(aHf, bLf, acc[r], 0, 0, 0);
            }
        }
    }

    const int col = wv * 16 + rl;
    const float blc = bl[col];
    #pragma unroll
    for (int r = 0; r < 4; ++r) {
        #pragma unroll
        for (int reg = 0; reg < 4; ++reg) {
            int row = r0 + r * 16 + kg * 4 + reg;
            if (row < N) {
                float sc = invs[batch_idx[row]];
                out[(size_t)row * 64 + col] = (acc[r][reg] + blc) * sc;
            }
        }
    }
}

// ---------------- launcher ----------------
extern "C" void kernel_launch(void* const* d_in, const int* in_sizes, int n_in,
                              void* d_out, int out_size, void* d_ws, size_t ws_size,
                              hipStream_t stream)
{
    const float* x      = (const float*)d_in[0];
    const float* mask   = (const float*)d_in[1];
    const int*   ei     = (const int*)d_in[2];
    const int*   batch  = (const int*)d_in[3];
    const float* Wg     = (const float*)d_in[4];
    const float* att_s  = (const float*)d_in[5];
    const float* att_d  = (const float*)d_in[6];
    const float* bias_g = (const float*)d_in[7];
    const float* Wl     = (const float*)d_in[8];
    const float* bl     = (const float*)d_in[9];
    float* out = (float*)d_out;

    const int N = in_sizes[0] / 64;   // 50000
    const int E = in_sizes[2] / 2;    // 800000

    char* w = (char*)d_ws;
    auto alloc = [&](size_t bytes) { char* p = w; w += (bytes + 255) & ~(size_t)255; return p; };
    uint32_t* xwp  = (uint32_t*)alloc((size_t)N * 128 * 4);
    uint32_t* tbp  = (uint32_t*)alloc((size_t)N * 128 * 4);
    float* a_s   = (float*)alloc((size_t)N * 4 * 4);
    float* a_d   = (float*)alloc((size_t)N * 4 * 4);
    unsigned long long* mbits = (unsigned long long*)alloc((size_t)N * 8);
    unsigned long long* magg  = (unsigned long long*)alloc((size_t)N * 8);
    int* deg    = (int*)alloc((size_t)N * 4);
    int* off    = (int*)alloc((size_t)(N + 1) * 4);
    int* cursor = (int*)alloc((size_t)N * 4);
    int* csr    = (int*)alloc((size_t)E * 4);
    int* bsum   = (int*)alloc(256 * 4);
    int* bpre   = (int*)alloc(256 * 4);
    int* startg = (int*)alloc(64 * 4);
    float* invs = (float*)alloc(64 * 4);

    int nbN4  = (N + 3) / 4;
    int nbE   = (E + 255) / 256;
    int nb256 = (N + 255) / 256;

    k_att2z<<<nb256, 256, 0, stream>>>(x, Wg, att_s, att_d, a_s, a_d, deg, magg, startg, N);
    k_maskdeg<<<nbN4 + nbE, 256, 0, stream>>>(mask, ei, mbits, deg, N, E, nbN4);
    k_gemm1m<<<(N + 63) / 64, 256, 0, stream>>>(x, Wg, batch, xwp, startg, N);
    k_scan1<<<nb256, 256, 0, stream>>>(deg, off, cursor, bsum, N);
    k_scan2<<<1, 256, 0, stream>>>(bsum, bpre, off, startg, invs, nb256, N);
    k_fill<<<nbE, 256, 0, stream>>>(ei, cursor, csr, bpre, mbits, magg, E);
    k_main7<<<2048, 256, 0, stream>>>(xwp, a_s, a_d, off, bpre, csr, magg, bias_g, tbp, N);
    k_gemm2m<<<(N + 63) / 64, 256, 0, stream>>>(tbp, Wl, bl, batch, invs, out, N);
}

// Round 16
// 230.581 us; speedup vs baseline: 1.1133x; 1.0217x over previous
//
#include <hip/hip_runtime.h>
#include <cstdint>
#include <math.h>

constexpr float NEG_SLOPE = 0.2f;

__device__ __forceinline__ float lrelu(float v) { return v > 0.0f ? v : NEG_SLOPE * v; }

// bf16 pack/unpack (RNE)
__device__ __forceinline__ unsigned short f2bf(float f) {
    uint32_t u = __float_as_uint(f);
    uint32_t r = (u + 0x7fffu + ((u >> 16) & 1u)) >> 16;
    return (unsigned short)r;
}
__device__ __forceinline__ float bf2f(unsigned short v) { return __uint_as_float((uint32_t)v << 16); }
__device__ __forceinline__ float bflo(uint32_t v) { return __uint_as_float(v << 16); }
__device__ __forceinline__ float bfhi(uint32_t v) { return __uint_as_float(v & 0xffff0000u); }

typedef short bf16x8 __attribute__((ext_vector_type(8)));   // 8 bf16 (4 VGPRs)
typedef float f32x4 __attribute__((ext_vector_type(4)));

// ---------------- K1: a_s/a_d per node + deg/magg zero + startg init ------------------
__launch_bounds__(256)
__global__ void k_att2z(const float* __restrict__ x, const float* __restrict__ Wg,
                        const float* __restrict__ att_s, const float* __restrict__ att_d,
                        float* __restrict__ a_s, float* __restrict__ a_d,
                        int* __restrict__ deg, unsigned long long* __restrict__ magg,
                        int* __restrict__ startg, int N)
{
    __shared__ float vs_l[256];
    __shared__ float vd_l[256];
    int tid = threadIdx.x;
    {   // vprep: vs[h][k] = sum_d Wg[h*64+d][k] * att_s[h][d]   (Wg 64KB, L2-hot)
        int h = tid >> 6, k = tid & 63;
        float s = 0.f, d = 0.f;
        for (int dd = 0; dd < 64; ++dd) {
            float w = Wg[(size_t)(h * 64 + dd) * 64 + k];
            s += w * att_s[h * 64 + dd];
            d += w * att_d[h * 64 + dd];
        }
        vs_l[tid] = s; vd_l[tid] = d;
    }
    if (blockIdx.x == 0 && tid < 64) startg[tid] = N;
    __syncthreads();
    int i = blockIdx.x * 256 + tid;
    if (i >= N) return;
    deg[i] = 0; magg[i] = 0ULL;
    const float4* xr = (const float4*)(x + (size_t)i * 64);
    float s0=0,s1=0,s2=0,s3=0, d0=0,d1=0,d2=0,d3=0;
    #pragma unroll
    for (int q = 0; q < 16; ++q) {
        float4 xv = xr[q];
        float4 a0 = *(const float4*)&vs_l[4*q];
        float4 a1 = *(const float4*)&vs_l[64 + 4*q];
        float4 a2 = *(const float4*)&vs_l[128 + 4*q];
        float4 a3 = *(const float4*)&vs_l[192 + 4*q];
        float4 c0 = *(const float4*)&vd_l[4*q];
        float4 c1 = *(const float4*)&vd_l[64 + 4*q];
        float4 c2 = *(const float4*)&vd_l[128 + 4*q];
        float4 c3 = *(const float4*)&vd_l[192 + 4*q];
        s0 += xv.x*a0.x + xv.y*a0.y + xv.z*a0.z + xv.w*a0.w;
        s1 += xv.x*a1.x + xv.y*a1.y + xv.z*a1.z + xv.w*a1.w;
        s2 += xv.x*a2.x + xv.y*a2.y + xv.z*a2.z + xv.w*a2.w;
        s3 += xv.x*a3.x + xv.y*a3.y + xv.z*a3.z + xv.w*a3.w;
        d0 += xv.x*c0.x + xv.y*c0.y + xv.z*c0.z + xv.w*c0.w;
        d1 += xv.x*c1.x + xv.y*c1.y + xv.z*c1.z + xv.w*c1.w;
        d2 += xv.x*c2.x + xv.y*c2.y + xv.z*c2.z + xv.w*c2.w;
        d3 += xv.x*c3.x + xv.y*c3.y + xv.z*c3.z + xv.w*c3.w;
    }
    *(float4*)&a_s[(size_t)i * 4] = make_float4(s0, s1, s2, s3);
    *(float4*)&a_d[(size_t)i * 4] = make_float4(d0, d1, d2, d3);
}

// ---------------- K2 (fused): mask ballot + deg histogram + Wg/Wl prebake -------------
// Range A [0,nbMask): mask ballot. Range B [nbMask,nbMask+nbE): deg histogram.
// Range C (32 blocks): WgB prebake. Range D (32 blocks): WlH/WlL prebake.
__global__ void k_maskdeg(const float* __restrict__ mask, const int* __restrict__ ei,
                          const float* __restrict__ Wg, const float* __restrict__ Wl,
                          unsigned long long* __restrict__ mbits, int* __restrict__ deg,
                          uint32_t* __restrict__ WgB, uint32_t* __restrict__ WlH,
                          uint32_t* __restrict__ WlL,
                          int N, int E, int nbMask, int nbE)
{
    int tid = threadIdx.x;
    int bid = blockIdx.x;
    if (bid < nbMask) {
        int wid  = (bid * 256 + tid) >> 6;
        int lane = tid & 63;
        if (wid >= N) return;
        float v = mask[(size_t)wid * 64 + lane];
        unsigned long long b = __ballot(v > 0.0f);
        if (lane == 0) mbits[wid] = b;
    } else if (bid < nbMask + nbE) {
        int e = (bid - nbMask) * 256 + tid;
        if (e >= E) return;
        atomicAdd(deg + ei[E + e], 1);
    } else if (bid < nbMask + nbE + 32) {
        int w = (bid - nbMask - nbE) * 256 + tid;     // [0,8192): c=w>>5, k2=w&31
        int c = w >> 5, k2 = w & 31;
        float2 v = *(const float2*)&Wg[(size_t)c * 64 + 2 * k2];
        WgB[w] = (uint32_t)f2bf(v.x) | ((uint32_t)f2bf(v.y) << 16);
    } else {
        int w = (bid - nbMask - nbE - 32) * 256 + tid; // [0,8192): c=w>>7, k2=w&127
        int c = w >> 7, k2 = w & 127;
        float2 v = *(const float2*)&Wl[(size_t)c * 256 + 2 * k2];
        unsigned short h0 = f2bf(v.x), h1 = f2bf(v.y);
        unsigned short l0 = f2bf(v.x - bf2f(h0)), l1 = f2bf(v.y - bf2f(h1));
        WlH[w] = (uint32_t)h0 | ((uint32_t)h1 << 16);
        WlL[w] = (uint32_t)l0 | ((uint32_t)l1 << 16);
    }
}

// ---------------- K3 (MFMA): xwp = x @ Wg^T; A LDS-staged, B from prebaked WgB --------
// WgB is 32KB -> L1-resident after first block per CU. LDS 48->16KB (occupancy 3->8+).
__launch_bounds__(256)
__global__ void k_gemm1m(const float* __restrict__ x, const uint32_t* __restrict__ WgB,
                         const int* __restrict__ batch_idx,
                         uint32_t* __restrict__ xwp, int* __restrict__ startg, int N)
{
    __shared__ __align__(16) uint32_t AsH[2048];   // 64 rows x 32 k-pairs (bf16x2)
    __shared__ __align__(16) uint32_t AsL[2048];
    const int tid = threadIdx.x;
    const int r0  = blockIdx.x * 64;

    for (int idx = tid; idx < 2048; idx += 256) {
        int r = idx >> 5, k2 = idx & 31;
        float2 v = make_float2(0.f, 0.f);
        if (r0 + r < N) v = *(const float2*)&x[(size_t)(r0 + r) * 64 + 2 * k2];
        unsigned short h0 = f2bf(v.x), h1 = f2bf(v.y);
        unsigned short l0 = f2bf(v.x - bf2f(h0)), l1 = f2bf(v.y - bf2f(h1));
        int di = (r * 32 + k2) ^ ((r & 7) << 2);
        AsH[di] = (uint32_t)h0 | ((uint32_t)h1 << 16);
        AsL[di] = (uint32_t)l0 | ((uint32_t)l1 << 16);
    }
    if (tid < 64 && (r0 + tid) < N) {
        int i = r0 + tid;
        int b = batch_idx[i];
        int pb = (i > 0) ? batch_idx[i - 1] : -1;
        if (b != pb) startg[b] = i;
    }
    __syncthreads();

    const int lane = tid & 63;
    const int wv   = tid >> 6;
    const int rl   = lane & 15;
    const int kg   = lane >> 4;
    const int ct0  = (wv & 1) * 2 + (wv >> 1) * 8;
    const int swz  = (rl & 7) << 2;

    f32x4 acc[4][4];
    #pragma unroll
    for (int r = 0; r < 4; ++r)
        #pragma unroll
        for (int cs = 0; cs < 4; ++cs) acc[r][cs] = (f32x4){0.f, 0.f, 0.f, 0.f};

    #pragma unroll
    for (int ks = 0; ks < 2; ++ks) {
        bf16x8 aH[4], aL[4], bH[4];
        #pragma unroll
        for (int r = 0; r < 4; ++r) {
            int ui = (((r * 16 + rl) * 32) + ks * 16 + kg * 4) ^ swz;
            aH[r] = *(const bf16x8*)&AsH[ui];
            aL[r] = *(const bf16x8*)&AsL[ui];
        }
        #pragma unroll
        for (int cs = 0; cs < 4; ++cs) {
            int ct = ct0 + (cs & 1) + (cs >> 1) * 4;
            bH[cs] = *(const bf16x8*)(WgB + ((ct * 16 + rl) * 32 + ks * 16 + kg * 4));
        }
        #pragma unroll
        for (int r = 0; r < 4; ++r)
            #pragma unroll
            for (int cs = 0; cs < 4; ++cs) {
                acc[r][cs] = __builtin_amdgcn_mfma_f32_16x16x32_bf16(aH[r], bH[cs], acc[r][cs], 0, 0, 0);
                acc[r][cs] = __builtin_amdgcn_mfma_f32_16x16x32_bf16(aL[r], bH[cs], acc[r][cs], 0, 0, 0);
            }
    }

    #pragma unroll
    for (int r = 0; r < 4; ++r) {
        #pragma unroll
        for (int reg = 0; reg < 4; ++reg) {
            int row = r0 + r * 16 + kg * 4 + reg;
            if (row < N) {
                #pragma unroll
                for (int p = 0; p < 2; ++p) {
                    int c_lo = (ct0 + p) * 16 + rl;
                    int wrd  = ((c_lo >> 7) << 6) | (c_lo & 63);
                    uint32_t lo = f2bf(acc[r][p][reg]);
                    uint32_t hi = f2bf(acc[r][p + 2][reg]);
                    xwp[(size_t)row * 128 + wrd] = lo | (hi << 16);
                }
            }
        }
    }
}

// ---------------- K5/K6: scan (scan3 eliminated via lazy bpre finalization) -----------
__global__ void k_scan1(const int* __restrict__ deg, int* __restrict__ off,
                        int* __restrict__ cursor, int* __restrict__ bsum, int N)
{
    __shared__ int s[256];
    int t = threadIdx.x;
    int i = blockIdx.x * 256 + t;
    int v = (i < N) ? deg[i] : 0;
    s[t] = v; __syncthreads();
    for (int o = 1; o < 256; o <<= 1) {
        int u = (t >= o) ? s[t - o] : 0;
        __syncthreads();
        s[t] += u;
        __syncthreads();
    }
    int incl = s[t];
    if (i < N) { off[i] = incl - v; cursor[i] = incl - v; }
    if (t == 255) bsum[blockIdx.x] = incl;
}

__global__ void k_scan2(const int* __restrict__ bsum, int* __restrict__ bpre,
                        int* __restrict__ off, const int* __restrict__ startg,
                        float* __restrict__ invs, int NB, int N)
{
    __shared__ int s[256];
    int t = threadIdx.x;
    int v = (t < NB) ? bsum[t] : 0;
    s[t] = v; __syncthreads();
    for (int o = 1; o < 256; o <<= 1) {
        int u = (t >= o) ? s[t - o] : 0;
        __syncthreads();
        s[t] += u;
        __syncthreads();
    }
    if (t < NB) bpre[t] = s[t] - v;
    if (t == 255) off[N] = s[255];   // grand total: FINAL (no bpre correction)
    if (t < 64) {
        int st = startg[t];
        int en = N;
        for (int g2 = t + 1; g2 < 64; ++g2) en = min(en, startg[g2]);
        int d = en - st;
        float dv = (d > 0) ? (float)d : 1.0f;
        invs[t] = 1.0f / sqrtf(dv);
    }
}

// ---------------- K_fill: CSR fill + mask OR scatter; position = partial + bpre -------
__global__ void k_fill(const int* __restrict__ ei, int* __restrict__ cursor,
                       int* __restrict__ csr, const int* __restrict__ bpre,
                       const unsigned long long* __restrict__ mbits,
                       unsigned long long* __restrict__ magg, int E)
{
    int e = blockIdx.x * blockDim.x + threadIdx.x;
    if (e >= E) return;
    int r = ei[e];
    int c = ei[E + e];
    unsigned long long b = mbits[c];
    if ((magg[r] & b) != b) atomicOr(magg + r, b);
    int pos = atomicAdd(cursor + c, 1) + bpre[c >> 8];
    csr[pos] = r;
}

// ---------------- K9 (v7 + lazy offsets): inline denominators, bf16 tb output ---------
__launch_bounds__(256)
__global__ void k_main7(const uint32_t* __restrict__ xwp,
                        const float* __restrict__ a_s,
                        const float* __restrict__ a_d,
                        const int* __restrict__ off,
                        const int* __restrict__ bpre,
                        const int* __restrict__ csr,
                        const unsigned long long* __restrict__ magg,
                        const float* __restrict__ bias,
                        uint32_t* __restrict__ tbp, int N)
{
    __shared__ __align__(16) uint32_t su[4][64];
    __shared__ __align__(16) float2 e01s[4][64];
    __shared__ __align__(16) float2 e23s[4][64];

    const int lane = threadIdx.x & 63;
    const int wv   = threadIdx.x >> 6;
    const int wid  = blockIdx.x * 4 + wv;
    const int nw   = gridDim.x * 4;
    const int hp   = lane >> 5;
    const int d0   = (lane & 31) * 2;

    const uint2* xw2 = (const uint2*)xwp;
    const float2 bsL = *(const float2*)&bias[hp * 128 + d0];
    const float2 bsH = *(const float2*)&bias[hp * 128 + 64 + d0];
    const float2* ep = hp ? e23s[wv] : e01s[wv];

    for (int i = wid; i < N; i += nw) {
        const int beg = off[i] + bpre[i >> 8];
        const int end = off[i + 1] + ((i + 1 < N) ? bpre[(i + 1) >> 8] : 0);
        const float4 adv = *(const float4*)(a_d + (size_t)i * 4);
        const float4 asv = *(const float4*)(a_s + (size_t)i * 4);
        const float ex0 = __expf(lrelu(asv.x + adv.x));
        const float ex1 = __expf(lrelu(asv.y + adv.y));
        const float ex2 = __expf(lrelu(asv.z + adv.z));
        const float ex3 = __expf(lrelu(asv.w + adv.w));

        const uint2 sv = xw2[(size_t)i * 64 + lane];
        const float wls = hp ? ex2 : ex0;
        const float whs = hp ? ex3 : ex1;
        float accL0 = wls * bflo(sv.x), accH0 = whs * bfhi(sv.x);
        float accL1 = wls * bflo(sv.y), accH1 = whs * bfhi(sv.y);
        float sL = 0.f, sH = 0.f;

        for (int kc = beg; kc < end; kc += 64) {
            const int cnt = min(64, end - kc);
            uint32_t sreg = 0; float e0 = 0.f, e1 = 0.f, e2 = 0.f, e3 = 0.f;
            if (lane < cnt) {
                sreg = csr[kc + lane];
                const float4 g = *(const float4*)(a_s + (size_t)sreg * 4);
                e0 = __expf(lrelu(g.x + adv.x));
                e1 = __expf(lrelu(g.y + adv.y));
                e2 = __expf(lrelu(g.z + adv.z));
                e3 = __expf(lrelu(g.w + adv.w));
            }
            su[wv][lane]   = sreg;
            e01s[wv][lane] = make_float2(e0, e1);
            e23s[wv][lane] = make_float2(e2, e3);

            int j = 0;
            for (; j + 8 <= cnt; j += 8) {
                uint4 sq0 = *(const uint4*)&su[wv][j];
                uint4 sq1 = *(const uint4*)&su[wv][j + 4];
                float2 w0 = ep[j],   w1 = ep[j+1], w2 = ep[j+2], w3 = ep[j+3];
                float2 w4 = ep[j+4], w5 = ep[j+5], w6 = ep[j+6], w7 = ep[j+7];
                uint2 v0 = xw2[(size_t)sq0.x * 64 + lane];
                uint2 v1 = xw2[(size_t)sq0.y * 64 + lane];
                uint2 v2 = xw2[(size_t)sq0.z * 64 + lane];
                uint2 v3 = xw2[(size_t)sq0.w * 64 + lane];
                uint2 v4 = xw2[(size_t)sq1.x * 64 + lane];
                uint2 v5 = xw2[(size_t)sq1.y * 64 + lane];
                uint2 v6 = xw2[(size_t)sq1.z * 64 + lane];
                uint2 v7 = xw2[(size_t)sq1.w * 64 + lane];
                sL += w0.x + w1.x + w2.x + w3.x + w4.x + w5.x + w6.x + w7.x;
                sH += w0.y + w1.y + w2.y + w3.y + w4.y + w5.y + w6.y + w7.y;
                accL0 += w0.x * bflo(v0.x); accH0 += w0.y * bfhi(v0.x);
                accL1 += w0.x * bflo(v0.y); accH1 += w0.y * bfhi(v0.y);
                accL0 += w1.x * bflo(v1.x); accH0 += w1.y * bfhi(v1.x);
                accL1 += w1.x * bflo(v1.y); accH1 += w1.y * bfhi(v1.y);
                accL0 += w2.x * bflo(v2.x); accH0 += w2.y * bfhi(v2.x);
                accL1 += w2.x * bflo(v2.y); accH1 += w2.y * bfhi(v2.y);
                accL0 += w3.x * bflo(v3.x); accH0 += w3.y * bfhi(v3.x);
                accL1 += w3.x * bflo(v3.y); accH1 += w3.y * bfhi(v3.y);
                accL0 += w4.x * bflo(v4.x); accH0 += w4.y * bfhi(v4.x);
                accL1 += w4.x * bflo(v4.y); accH1 += w4.y * bfhi(v4.y);
                accL0 += w5.x * bflo(v5.x); accH0 += w5.y * bfhi(v5.x);
                accL1 += w5.x * bflo(v5.y); accH1 += w5.y * bfhi(v5.y);
                accL0 += w6.x * bflo(v6.x); accH0 += w6.y * bfhi(v6.x);
                accL1 += w6.x * bflo(v6.y); accH1 += w6.y * bfhi(v6.y);
                accL0 += w7.x * bflo(v7.x); accH0 += w7.y * bfhi(v7.x);
                accL1 += w7.x * bflo(v7.y); accH1 += w7.y * bfhi(v7.y);
            }
            for (; j + 4 <= cnt; j += 4) {
                uint4 sq = *(const uint4*)&su[wv][j];
                float2 wA = ep[j], wB = ep[j+1], wC = ep[j+2], wD = ep[j+3];
                uint2 vA = xw2[(size_t)sq.x * 64 + lane];
                uint2 vB = xw2[(size_t)sq.y * 64 + lane];
                uint2 vC = xw2[(size_t)sq.z * 64 + lane];
                uint2 vD = xw2[(size_t)sq.w * 64 + lane];
                sL += wA.x + wB.x + wC.x + wD.x;
                sH += wA.y + wB.y + wC.y + wD.y;
                accL0 += wA.x * bflo(vA.x); accH0 += wA.y * bfhi(vA.x);
                accL1 += wA.x * bflo(vA.y); accH1 += wA.y * bfhi(vA.y);
                accL0 += wB.x * bflo(vB.x); accH0 += wB.y * bfhi(vB.x);
                accL1 += wB.x * bflo(vB.y); accH1 += wB.y * bfhi(vB.y);
                accL0 += wC.x * bflo(vC.x); accH0 += wC.y * bfhi(vC.x);
                accL1 += wC.x * bflo(vC.y); accH1 += wC.y * bfhi(vC.y);
                accL0 += wD.x * bflo(vD.x); accH0 += wD.y * bfhi(vD.x);
                accL1 += wD.x * bflo(vD.y); accH1 += wD.y * bfhi(vD.y);
            }
            for (; j < cnt; ++j) {
                uint32_t s = su[wv][j];
                float2 wE = ep[j];
                uint2 v = xw2[(size_t)s * 64 + lane];
                sL += wE.x; sH += wE.y;
                accL0 += wE.x * bflo(v.x); accH0 += wE.y * bfhi(v.x);
                accL1 += wE.x * bflo(v.y); accH1 += wE.y * bfhi(v.y);
            }
        }
        const float rlo = 1.0f / (sL + wls + 1e-16f);
        const float rhi = 1.0f / (sH + whs + 1e-16f);

        const unsigned long long mb = magg[i];
        const float m0 = (float)((mb >> d0) & 1ULL);
        const float m1 = (float)((mb >> (d0 + 1)) & 1ULL);
        float oL0 = (accL0 * rlo + bsL.x) * m0, oL1 = (accL1 * rlo + bsL.y) * m1;
        float oH0 = (accH0 * rhi + bsH.x) * m0, oH1 = (accH1 * rhi + bsH.y) * m1;
        tbp[(size_t)i * 128 + hp * 64 + (lane & 31)]      = (uint32_t)f2bf(oL0) | ((uint32_t)f2bf(oL1) << 16);
        tbp[(size_t)i * 128 + hp * 64 + 32 + (lane & 31)] = (uint32_t)f2bf(oH0) | ((uint32_t)f2bf(oH1) << 16);
    }
}

// ---------------- K10 (MFMA): out = tbp(bf16) @ Wl^T + bl; A LDS-staged, B prebaked ---
__launch_bounds__(256)
__global__ void k_gemm2m(const uint32_t* __restrict__ tbp, const uint32_t* __restrict__ WlH,
                         const uint32_t* __restrict__ WlL, const float* __restrict__ bl,
                         const int* __restrict__ batch_idx, const float* __restrict__ invs,
                         float* __restrict__ out, int N)
{
    __shared__ __align__(16) uint32_t AH[2048];   // 64 rows x 32 k-pairs
    const int tid = threadIdx.x;
    const int r0  = blockIdx.x * 64;
    const int lane = tid & 63;
    const int wv   = tid >> 6;
    const int rl   = lane & 15;
    const int kg   = lane >> 4;
    const int swz  = (rl & 7) << 2;
    const int col  = wv * 16 + rl;

    f32x4 acc[4];
    #pragma unroll
    for (int r = 0; r < 4; ++r) acc[r] = (f32x4){0.f, 0.f, 0.f, 0.f};

    const uint32_t* wbH = WlH + col * 128;
    const uint32_t* wbL = WlL + col * 128;

    for (int kc = 0; kc < 4; ++kc) {
        if (kc) __syncthreads();
        for (int idx = tid; idx < 2048; idx += 256) {
            int r = idx >> 5, k2 = idx & 31;
            uint32_t v = 0;
            if (r0 + r < N) v = tbp[(size_t)(r0 + r) * 128 + kc * 32 + k2];
            AH[(r * 32 + k2) ^ ((r & 7) << 2)] = v;
        }
        __syncthreads();

        #pragma unroll
        for (int ks = 0; ks < 2; ++ks) {
            const int wo = kc * 32 + ks * 16 + kg * 4;
            bf16x8 bHf = *(const bf16x8*)(wbH + wo);
            bf16x8 bLf = *(const bf16x8*)(wbL + wo);
            #pragma unroll
            for (int r = 0; r < 4; ++r) {
                int ui = ((r * 16 + rl) * 32 + ks * 16 + kg * 4) ^ swz;
                bf16x8 aHf = *(const bf16x8*)&AH[ui];
                acc[r] = __builtin_amdgcn_mfma_f32_16x16x32_bf16(aHf, bHf, acc[r], 0, 0, 0);
                acc[r] = __builtin_amdgcn_mfma_f32_16x16x32_bf16(aHf, bLf, acc[r], 0, 0, 0);
            }
        }
    }

    const float blc = bl[col];
    #pragma unroll
    for (int r = 0; r < 4; ++r) {
        #pragma unroll
        for (int reg = 0; reg < 4; ++reg) {
            int row = r0 + r * 16 + kg * 4 + reg;
            if (row < N) {
                float sc = invs[batch_idx[row]];
                out[(size_t)row * 64 + col] = (acc[r][reg] + blc) * sc;
            }
        }
    }
}

// ---------------- launcher ----------------
extern "C" void kernel_launch(void* const* d_in, const int* in_sizes, int n_in,
                              void* d_out, int out_size, void* d_ws, size_t ws_size,
                              hipStream_t stream)
{
    const float* x      = (const float*)d_in[0];
    const float* mask   = (const float*)d_in[1];
    const int*   ei     = (const int*)d_in[2];
    const int*   batch  = (const int*)d_in[3];
    const float* Wg     = (const float*)d_in[4];
    const float* att_s  = (const float*)d_in[5];
    const float* att_d  = (const float*)d_in[6];
    const float* bias_g = (const float*)d_in[7];
    const float* Wl     = (const float*)d_in[8];
    const float* bl     = (const float*)d_in[9];
    float* out = (float*)d_out;

    const int N = in_sizes[0] / 64;   // 50000
    const int E = in_sizes[2] / 2;    // 800000

    char* w = (char*)d_ws;
    auto alloc = [&](size_t bytes) { char* p = w; w += (bytes + 255) & ~(size_t)255; return p; };
    uint32_t* xwp  = (uint32_t*)alloc((size_t)N * 128 * 4);
    uint32_t* tbp  = (uint32_t*)alloc((size_t)N * 128 * 4);
    float* a_s   = (float*)alloc((size_t)N * 4 * 4);
    float* a_d   = (float*)alloc((size_t)N * 4 * 4);
    unsigned long long* mbits = (unsigned long long*)alloc((size_t)N * 8);
    unsigned long long* magg  = (unsigned long long*)alloc((size_t)N * 8);
    int* deg    = (int*)alloc((size_t)N * 4);
    int* off    = (int*)alloc((size_t)(N + 1) * 4);
    int* cursor = (int*)alloc((size_t)N * 4);
    int* csr    = (int*)alloc((size_t)E * 4);
    int* bsum   = (int*)alloc(256 * 4);
    int* bpre   = (int*)alloc(256 * 4);
    int* startg = (int*)alloc(64 * 4);
    float* invs = (float*)alloc(64 * 4);
    uint32_t* WgB = (uint32_t*)alloc(8192 * 4);
    uint32_t* WlH = (uint32_t*)alloc(8192 * 4);
    uint32_t* WlL = (uint32_t*)alloc(8192 * 4);

    int nbN4  = (N + 3) / 4;
    int nbE   = (E + 255) / 256;
    int nb256 = (N + 255) / 256;

    k_att2z<<<nb256, 256, 0, stream>>>(x, Wg, att_s, att_d, a_s, a_d, deg, magg, startg, N);
    k_maskdeg<<<nbN4 + nbE + 64, 256, 0, stream>>>(mask, ei, Wg, Wl, mbits, deg, WgB, WlH, WlL, N, E, nbN4, nbE);
    k_gemm1m<<<(N + 63) / 64, 256, 0, stream>>>(x, WgB, batch, xwp, startg, N);
    k_scan1<<<nb256, 256, 0, stream>>>(deg, off, cursor, bsum, N);
    k_scan2<<<1, 256, 0, stream>>>(bsum, bpre, off, startg, invs, nb256, N);
    k_fill<<<nbE, 256, 0, stream>>>(ei, cursor, csr, bpre, mbits, magg, E);
    k_main7<<<2048, 256, 0, stream>>>(xwp, a_s, a_d, off, bpre, csr, magg, bias_g, tbp, N);
    k_gemm2m<<<(N + 63) / 64, 256, 0, stream>>>(tbp, WlH, WlL, bl, batch, invs, out, N);
}